// Round 2
// baseline (401.060 us; speedup 1.0000x reference)
//
#include <hip/hip_runtime.h>
#include <stdint.h>

using u16 = unsigned short;
using short8 = __attribute__((ext_vector_type(8))) short;
using f32x4  = __attribute__((ext_vector_type(4))) float;
using u32x4  = __attribute__((ext_vector_type(4))) unsigned int;

__device__ __forceinline__ float bf2f(u16 u) {
  return __builtin_bit_cast(float, ((unsigned)u) << 16);
}
__device__ __forceinline__ u16 f2bf(float f) {
  unsigned u = __builtin_bit_cast(unsigned, f);
  u += 0x7FFFu + ((u >> 16) & 1u);   // RNE
  return (u16)(u >> 16);
}

// ---------------- 3-NN + inverse-distance weights (fp32 in) ----------------
// grid (N/256, B), block 256. One thread per query point n.
__global__ __launch_bounds__(256) void nn3_kernel(
    const float* __restrict__ xyz1, const float* __restrict__ xyz2,
    int* __restrict__ idx_out, float* __restrict__ w_out) {
  __shared__ float xs[1024], ys[1024], zs[1024], r2s[1024];
  const int b = blockIdx.y;
  const int t = threadIdx.x;
  const float* x2 = xyz2 + b * 3072;
  for (int i = t; i < 1024; i += 256) {
    xs[i] = x2[i];
    ys[i] = x2[1024 + i];
    zs[i] = x2[2048 + i];
  }
  __syncthreads();
  for (int i = t; i < 1024; i += 256)
    r2s[i] = xs[i]*xs[i] + ys[i]*ys[i] + zs[i]*zs[i];
  __syncthreads();
  const int n = blockIdx.x * 256 + t;
  const float* x1 = xyz1 + b * 12288;
  const float px = x1[n], py = x1[4096 + n], pz = x1[8192 + n];
  const float r1 = px*px + py*py + pz*pz;
  float d0 = 1e30f, d1 = 1e30f, d2 = 1e30f;
  int i0 = 0, i1 = 0, i2 = 0;
  for (int s = 0; s < 1024; ++s) {
    float dot = px*xs[s] + py*ys[s] + pz*zs[s];
    float d = (r1 + r2s[s]) - 2.0f*dot;  // same |a|^2+|b|^2-2ab expansion as reference
    if (d < d2) {
      if (d < d1) {
        d2 = d1; i2 = i1;
        if (d < d0) { d1 = d0; i1 = i0; d0 = d; i0 = s; }
        else        { d1 = d;  i1 = s; }
      } else       { d2 = d;  i2 = s; }
    }
  }
  float w0 = 1.0f/(d0 + 1e-8f), w1 = 1.0f/(d1 + 1e-8f), w2 = 1.0f/(d2 + 1e-8f);
  float inv = 1.0f/(w0 + w1 + w2);
  const int pos = b * 4096 + n;
  idx_out[pos*3+0] = i0; idx_out[pos*3+1] = i1; idx_out[pos*3+2] = i2;
  w_out[pos*3+0] = w0*inv; w_out[pos*3+1] = w1*inv; w_out[pos*3+2] = w2*inv;
}

// ---------------- [C=256][L] fp32 -> [L][C] bf16 transpose ----------------
// grid (L/64, 256/64, B), block 256.
__global__ __launch_bounds__(256) void transpose_cl(
    const float* __restrict__ in, u16* __restrict__ out, int L, int rstride) {
  __shared__ u16 tile[64][66];
  const int b = blockIdx.z;
  in  += (size_t)b * 256 * L;
  out += (size_t)b * L * rstride;
  const int n0 = blockIdx.x * 64, c0 = blockIdx.y * 64;
  const int t = threadIdx.x, ln = t & 63, grp = t >> 6;
  for (int p = 0; p < 16; ++p) {
    int cc = p*4 + grp;
    tile[cc][ln] = f2bf(in[(size_t)(c0 + cc) * L + n0 + ln]);
  }
  __syncthreads();
  for (int p = 0; p < 16; ++p) {
    int nn = p*4 + grp;
    out[(size_t)(n0 + nn) * rstride + c0 + ln] = tile[ln][nn];
  }
}

// ---------------- fp32 -> bf16 weight conversion ----------------
__global__ __launch_bounds__(256) void cvt_kernel(const float* __restrict__ in,
                                                  u16* __restrict__ out, int n) {
  int i = blockIdx.x * 256 + threadIdx.x;
  if (i < n) out[i] = f2bf(in[i]);
}

// ---------------- 3-NN feature interpolation into A1 cols 256..511 ----------------
// grid 4096 (16 positions each), block 256 (one thread per channel c).
__global__ __launch_bounds__(256) void interp_kernel(
    const u16* __restrict__ p2t, const int* __restrict__ idx,
    const float* __restrict__ wgt, u16* __restrict__ A1) {
  const int t = threadIdx.x;
  const int base = blockIdx.x * 16;
  for (int i = 0; i < 16; ++i) {
    const int pos = base + i;
    const int b = pos >> 12;
    const int j0 = idx[pos*3+0], j1 = idx[pos*3+1], j2 = idx[pos*3+2];
    const float w0 = wgt[pos*3+0], w1 = wgt[pos*3+1], w2 = wgt[pos*3+2];
    const u16* r0 = p2t + ((size_t)(b*1024 + j0)) * 256;
    const u16* r1 = p2t + ((size_t)(b*1024 + j1)) * 256;
    const u16* r2 = p2t + ((size_t)(b*1024 + j2)) * 256;
    float v = w0*bf2f(r0[t]) + w1*bf2f(r1[t]) + w2*bf2f(r2[t]);
    A1[(size_t)pos*512 + 256 + t] = f2bf(v);
  }
}

// ---------------- bf16 GEMM: Y[m][n] = sum_k A[m][k]*Bw[n][k] + bias[n] ----------------
// A: [M][K] bf16; Bw: [N][K] bf16; bias fp32; Y: [M][256] bf16.
// grid (M/128, N/128), block 256 (4 waves, 2x2 of 64x64 per wave).
__global__ __launch_bounds__(256) void gemm_kernel(
    const u16* __restrict__ A, const u16* __restrict__ Bw,
    const float* __restrict__ bias, u16* __restrict__ Y, int K) {
  // stride 48 u16 = 96 B: keeps every b128 LDS access 16B-aligned; per-bank
  // phase count works out to the minimal 8/wave (conflict-free).
  __shared__ __align__(16) u16 As[128*48];
  __shared__ __align__(16) u16 Bs[128*48];
  const int t = threadIdx.x;
  const int m0 = blockIdx.x * 128, n0 = blockIdx.y * 128;
  const int wave = t >> 6, l = t & 63;
  const int wm = wave & 1, wn = wave >> 1;
  const int lc = l & 15, quad = l >> 4;
  f32x4 acc[4][4] = {};
  const int rowA = t >> 2, kc = (t & 3) * 8;
  for (int k0 = 0; k0 < K; k0 += 32) {
    *(u32x4*)&As[rowA*48 + kc]      = *(const u32x4*)&A[(size_t)(m0 + rowA)*K + k0 + kc];
    *(u32x4*)&As[(rowA+64)*48 + kc] = *(const u32x4*)&A[(size_t)(m0 + rowA + 64)*K + k0 + kc];
    *(u32x4*)&Bs[rowA*48 + kc]      = *(const u32x4*)&Bw[(size_t)(n0 + rowA)*K + k0 + kc];
    *(u32x4*)&Bs[(rowA+64)*48 + kc] = *(const u32x4*)&Bw[(size_t)(n0 + rowA + 64)*K + k0 + kc];
    __syncthreads();
    short8 af[4], bfv[4];
    for (int tm = 0; tm < 4; ++tm)
      af[tm] = *(const short8*)&As[(wm*64 + tm*16 + lc)*48 + quad*8];   // A[m=lane&15][k=quad*8+j]
    for (int tn = 0; tn < 4; ++tn)
      bfv[tn] = *(const short8*)&Bs[(wn*64 + tn*16 + lc)*48 + quad*8];  // B[k=quad*8+j][n=lane&15]
    for (int tm = 0; tm < 4; ++tm)
      for (int tn = 0; tn < 4; ++tn)
        acc[tm][tn] = __builtin_amdgcn_mfma_f32_16x16x32_bf16(af[tm], bfv[tn], acc[tm][tn], 0, 0, 0);
    __syncthreads();
  }
  for (int tn = 0; tn < 4; ++tn) {
    const int col = n0 + wn*64 + tn*16 + lc;
    const float bb = bias[col];
    for (int tm = 0; tm < 4; ++tm) {
      const int row = m0 + wm*64 + tm*16 + quad*4;
      for (int r = 0; r < 4; ++r)
        Y[(size_t)(row + r)*256 + col] = f2bf(acc[tm][tn][r] + bb);  // C/D: col=lane&15, row=quad*4+reg
    }
  }
}

// ---------------- per-channel sum / sumsq over Y[65536][256] (bf16) ----------------
__global__ __launch_bounds__(256) void colstats_kernel(
    const u16* __restrict__ Y, float* __restrict__ sums, float* __restrict__ sumsq) {
  const int t = threadIdx.x;
  size_t base = (size_t)blockIdx.x * 256 * 256;
  float s = 0.0f, q = 0.0f;
  for (int r = 0; r < 256; ++r) {
    float v = bf2f(Y[base + (size_t)r*256 + t]);
    s += v; q += v*v;
  }
  atomicAdd(&sums[t], s);
  atomicAdd(&sumsq[t], q);
}

__global__ void bnprep_kernel(const float* __restrict__ sums, const float* __restrict__ sumsq,
                              const float* __restrict__ g, const float* __restrict__ be,
                              float* __restrict__ scale, float* __restrict__ shift) {
  const int t = threadIdx.x;
  const float inv_n = 1.0f / 65536.0f;
  float mean = sums[t] * inv_n;
  float var = sumsq[t] * inv_n - mean*mean;  // biased var, matches jnp.var
  float a = g[t] * rsqrtf(var + 1e-5f);
  scale[t] = a;
  shift[t] = be[t] - mean * a;
}

// ---------------- BN+ReLU, pos-major bf16 output (GEMM2 input) ----------------
__global__ __launch_bounds__(256) void bnrelu_kernel(
    const u16* __restrict__ Y, const float* __restrict__ scale,
    const float* __restrict__ shift, u16* __restrict__ X) {
  const int t = threadIdx.x;
  const float a = scale[t], s = shift[t];
  size_t base = (size_t)blockIdx.x * 16 * 256;
  for (int r = 0; r < 16; ++r) {
    float v = bf2f(Y[base + r*256 + t]) * a + s;
    X[base + r*256 + t] = f2bf(v > 0.0f ? v : 0.0f);
  }
}

// ---------------- BN+ReLU + transpose to [b][c][n] fp32 output ----------------
// grid (64, 1, 16), block 256 (thread = channel).
__global__ __launch_bounds__(256) void bnrelu_tr_kernel(
    const u16* __restrict__ Y, const float* __restrict__ scale,
    const float* __restrict__ shift, float* __restrict__ out) {
  __shared__ u16 tile[256][66];
  const int t = threadIdx.x;
  const int b = blockIdx.z;
  const int n0 = blockIdx.x * 64;
  const float a = scale[t], s = shift[t];
  for (int nn = 0; nn < 64; ++nn) {
    size_t pos = (size_t)b*4096 + n0 + nn;
    float v = bf2f(Y[pos*256 + t]) * a + s;
    tile[t][nn] = f2bf(v > 0.0f ? v : 0.0f);
  }
  __syncthreads();
  const int ln = t & 63, grp = t >> 6;
  for (int p = 0; p < 64; ++p) {
    int oo = p*4 + grp;
    out[((size_t)b*256 + oo)*4096 + n0 + ln] = bf2f(tile[oo][ln]);
  }
}

extern "C" void kernel_launch(void* const* d_in, const int* in_sizes, int n_in,
                              void* d_out, int out_size, void* d_ws, size_t ws_size,
                              hipStream_t stream) {
  const float* xyz1    = (const float*)d_in[0];
  const float* xyz2    = (const float*)d_in[1];
  const float* points1 = (const float*)d_in[2];
  const float* points2 = (const float*)d_in[3];
  const float* w0      = (const float*)d_in[4];
  const float* b0      = (const float*)d_in[5];
  const float* g0      = (const float*)d_in[6];
  const float* be0     = (const float*)d_in[7];
  const float* w1      = (const float*)d_in[8];
  const float* b1      = (const float*)d_in[9];
  const float* g1      = (const float*)d_in[10];
  const float* be1     = (const float*)d_in[11];
  float* out = (float*)d_out;

  // ---- workspace layout (~107 MiB used; round-1 run proved ws >= 128 MiB) ----
  char* ws = (char*)d_ws;
  u16*   A1   = (u16*)ws;                          // [65536][512] bf16, 64 MiB (dead after gemm1)
  u16*   X0   = (u16*)ws;                          // [65536][256] bf16, 32 MiB (overlays dead A1)
  u16*   Y    = (u16*)(ws + (64ull  << 20));       // [65536][256] bf16, 32 MiB
  u16*   p2t  = (u16*)(ws + (96ull  << 20));       // [16*1024][256] bf16, 8 MiB
  int*   idxb = (int*)(ws + (104ull << 20));       // 768 KiB
  float* wgtb = (float*)(ws + (105ull << 20));     // 768 KiB
  u16*   w0b  = (u16*)(ws + (106ull << 20));       // [256][512] bf16, 256 KiB
  u16*   w1b  = (u16*)(ws + (106ull << 20) + (256u << 10)); // [256][256] bf16, 128 KiB
  float* stats= (float*)(ws + (106ull << 20) + (512u << 10)); // 2048 floats

  float* sums0 = stats, *sumsq0 = stats + 256, *scale0 = stats + 512, *shift0 = stats + 768;
  float* sums1 = stats + 1024, *sumsq1 = stats + 1280, *scale1 = stats + 1536, *shift1 = stats + 1792;

  hipMemsetAsync(stats, 0, 2048 * sizeof(float), stream);
  nn3_kernel<<<dim3(16, 16), 256, 0, stream>>>(xyz1, xyz2, idxb, wgtb);
  transpose_cl<<<dim3(16, 4, 16), 256, 0, stream>>>(points2, p2t, 1024, 256);
  transpose_cl<<<dim3(64, 4, 16), 256, 0, stream>>>(points1, A1, 4096, 512);
  cvt_kernel<<<512, 256, 0, stream>>>(w0, w0b, 131072);
  cvt_kernel<<<256, 256, 0, stream>>>(w1, w1b, 65536);
  interp_kernel<<<4096, 256, 0, stream>>>(p2t, idxb, wgtb, A1);
  gemm_kernel<<<dim3(512, 2), 256, 0, stream>>>(A1, w0b, b0, Y, 512);
  colstats_kernel<<<256, 256, 0, stream>>>(Y, sums0, sumsq0);
  bnprep_kernel<<<1, 256, 0, stream>>>(sums0, sumsq0, g0, be0, scale0, shift0);
  bnrelu_kernel<<<4096, 256, 0, stream>>>(Y, scale0, shift0, X0);
  gemm_kernel<<<dim3(512, 2), 256, 0, stream>>>(X0, w1b, b1, Y, 256);
  colstats_kernel<<<256, 256, 0, stream>>>(Y, sums1, sumsq1);
  bnprep_kernel<<<1, 256, 0, stream>>>(sums1, sumsq1, g1, be1, scale1, shift1);
  bnrelu_tr_kernel<<<dim3(64, 1, 16), 256, 0, stream>>>(Y, scale1, shift1, out);
}

// Round 3
// 331.477 us; speedup vs baseline: 1.2099x; 1.2099x over previous
//
#include <hip/hip_runtime.h>
#include <stdint.h>

using u16 = unsigned short;
using short8 = __attribute__((ext_vector_type(8))) short;
using f32x4  = __attribute__((ext_vector_type(4))) float;
using u32x4  = __attribute__((ext_vector_type(4))) unsigned int;

__device__ __forceinline__ float bf2f(u16 u) {
  return __builtin_bit_cast(float, ((unsigned)u) << 16);
}
__device__ __forceinline__ u16 f2bf(float f) {
  unsigned u = __builtin_bit_cast(unsigned, f);
  u += 0x7FFFu + ((u >> 16) & 1u);   // RNE
  return (u16)(u >> 16);
}

// branchless insert of (d,s) into sorted top-3; strict < keeps earlier entries on ties
__device__ __forceinline__ void ins3(float& d0, float& d1, float& d2,
                                     int& i0, int& i1, int& i2, float d, int s) {
  bool c0 = d < d0, c1 = d < d1, c2 = d < d2;
  d2 = c1 ? d1 : (c2 ? d : d2);
  i2 = c1 ? i1 : (c2 ? s : i2);
  d1 = c0 ? d0 : (c1 ? d : d1);
  i1 = c0 ? i0 : (c1 ? s : i1);
  d0 = c0 ? d : d0;
  i0 = c0 ? s : i0;
}

// ---------------- 3-NN + inverse-distance weights (fp32 in) ----------------
// grid (N/64, B), block 256. 4 threads per query, each scans 256 candidates;
// partial top-3s merged via shfl_xor (lanes 4q..4q+3 are in the same wave).
__global__ __launch_bounds__(256) void nn3_kernel(
    const float* __restrict__ xyz1, const float* __restrict__ xyz2,
    int* __restrict__ idx_out, float* __restrict__ w_out) {
  __shared__ __align__(16) float cand[1024][4];  // x,y,z,r2 interleaved -> 1 ds_read_b128/cand
  const int b = blockIdx.y;
  const int t = threadIdx.x;
  const float* x2 = xyz2 + b * 3072;
  for (int i = t; i < 1024; i += 256) {
    float x = x2[i], y = x2[1024 + i], z = x2[2048 + i];
    cand[i][0] = x; cand[i][1] = y; cand[i][2] = z;
    cand[i][3] = x*x + y*y + z*z;
  }
  __syncthreads();
  const int q = t >> 2, sub = t & 3;
  const int n = blockIdx.x * 64 + q;
  const float* x1 = xyz1 + b * 12288;
  const float px = x1[n], py = x1[4096 + n], pz = x1[8192 + n];
  const float r1 = px*px + py*py + pz*pz;
  float d0 = 1e30f, d1 = 1e30f, d2 = 1e30f;
  int i0 = 0, i1 = 0, i2 = 0;
  const int sbeg = sub << 8;
  #pragma unroll 4
  for (int s = sbeg; s < sbeg + 256; ++s) {
    f32x4 c = *(const f32x4*)cand[s];
    float dot = px*c[0] + py*c[1] + pz*c[2];
    float d = (r1 + c[3]) - 2.0f*dot;  // same expansion + scan-order ties as before
    ins3(d0, d1, d2, i0, i1, i2, d, s);
  }
  // merge 4 partial lists: stage 1 pairs (0,1),(2,3); stage 2 pairs halves.
  // a-list is always the lower-index range on the lanes whose result we consume.
  for (int st = 1; st <= 2; st <<= 1) {
    float e0 = __shfl_xor(d0, st), e1 = __shfl_xor(d1, st), e2 = __shfl_xor(d2, st);
    int   j0 = __shfl_xor(i0, st), j1 = __shfl_xor(i1, st), j2 = __shfl_xor(i2, st);
    ins3(d0, d1, d2, i0, i1, i2, e0, j0);
    ins3(d0, d1, d2, i0, i1, i2, e1, j1);
    ins3(d0, d1, d2, i0, i1, i2, e2, j2);
  }
  if (sub == 0) {
    float w0 = 1.0f/(d0 + 1e-8f), w1 = 1.0f/(d1 + 1e-8f), w2 = 1.0f/(d2 + 1e-8f);
    float inv = 1.0f/(w0 + w1 + w2);
    const int pos = b * 4096 + n;
    idx_out[pos*3+0] = i0; idx_out[pos*3+1] = i1; idx_out[pos*3+2] = i2;
    w_out[pos*3+0] = w0*inv; w_out[pos*3+1] = w1*inv; w_out[pos*3+2] = w2*inv;
  }
}

// ---------------- [C=256][L] fp32 -> [L][C] bf16 transpose ----------------
// grid (L/64, 256/64, B), block 256.
__global__ __launch_bounds__(256) void transpose_cl(
    const float* __restrict__ in, u16* __restrict__ out, int L, int rstride) {
  __shared__ u16 tile[64][66];
  const int b = blockIdx.z;
  in  += (size_t)b * 256 * L;
  out += (size_t)b * L * rstride;
  const int n0 = blockIdx.x * 64, c0 = blockIdx.y * 64;
  const int t = threadIdx.x, ln = t & 63, grp = t >> 6;
  for (int p = 0; p < 16; ++p) {
    int cc = p*4 + grp;
    tile[cc][ln] = f2bf(in[(size_t)(c0 + cc) * L + n0 + ln]);
  }
  __syncthreads();
  for (int p = 0; p < 16; ++p) {
    int nn = p*4 + grp;
    out[(size_t)(n0 + nn) * rstride + c0 + ln] = tile[ln][nn];
  }
}

// ---------------- fp32 -> bf16 weight conversion ----------------
__global__ __launch_bounds__(256) void cvt_kernel(const float* __restrict__ in,
                                                  u16* __restrict__ out, int n) {
  int i = blockIdx.x * 256 + threadIdx.x;
  if (i < n) out[i] = f2bf(in[i]);
}

// ---------------- 3-NN feature interpolation into A1 cols 256..511 ----------------
// grid 4096 (16 positions each), block 256 (one thread per channel c).
__global__ __launch_bounds__(256) void interp_kernel(
    const u16* __restrict__ p2t, const int* __restrict__ idx,
    const float* __restrict__ wgt, u16* __restrict__ A1) {
  const int t = threadIdx.x;
  const int base = blockIdx.x * 16;
  for (int i = 0; i < 16; ++i) {
    const int pos = base + i;
    const int b = pos >> 12;
    const int j0 = idx[pos*3+0], j1 = idx[pos*3+1], j2 = idx[pos*3+2];
    const float w0 = wgt[pos*3+0], w1 = wgt[pos*3+1], w2 = wgt[pos*3+2];
    const u16* r0 = p2t + ((size_t)(b*1024 + j0)) * 256;
    const u16* r1 = p2t + ((size_t)(b*1024 + j1)) * 256;
    const u16* r2 = p2t + ((size_t)(b*1024 + j2)) * 256;
    float v = w0*bf2f(r0[t]) + w1*bf2f(r1[t]) + w2*bf2f(r2[t]);
    A1[(size_t)pos*512 + 256 + t] = f2bf(v);
  }
}

// ---------------- bf16 GEMM: Y[m][n] = sum_k A[m][k]*Bw[n][k] + bias[n] ----------------
// A: [M][K] bf16; Bw: [N][K] bf16; bias fp32; Y: [M][256] bf16.
// grid (M/128, N/128), block 256 (4 waves, 2x2 of 64x64 per wave).
__global__ __launch_bounds__(256) void gemm_kernel(
    const u16* __restrict__ A, const u16* __restrict__ Bw,
    const float* __restrict__ bias, u16* __restrict__ Y, int K) {
  // stride 48 u16 = 96 B: keeps every b128 LDS access 16B-aligned, conflict-free.
  __shared__ __align__(16) u16 As[128*48];
  __shared__ __align__(16) u16 Bs[128*48];
  const int t = threadIdx.x;
  const int m0 = blockIdx.x * 128, n0 = blockIdx.y * 128;
  const int wave = t >> 6, l = t & 63;
  const int wm = wave & 1, wn = wave >> 1;
  const int lc = l & 15, quad = l >> 4;
  f32x4 acc[4][4] = {};
  const int rowA = t >> 2, kc = (t & 3) * 8;
  for (int k0 = 0; k0 < K; k0 += 32) {
    *(u32x4*)&As[rowA*48 + kc]      = *(const u32x4*)&A[(size_t)(m0 + rowA)*K + k0 + kc];
    *(u32x4*)&As[(rowA+64)*48 + kc] = *(const u32x4*)&A[(size_t)(m0 + rowA + 64)*K + k0 + kc];
    *(u32x4*)&Bs[rowA*48 + kc]      = *(const u32x4*)&Bw[(size_t)(n0 + rowA)*K + k0 + kc];
    *(u32x4*)&Bs[(rowA+64)*48 + kc] = *(const u32x4*)&Bw[(size_t)(n0 + rowA + 64)*K + k0 + kc];
    __syncthreads();
    short8 af[4], bfv[4];
    for (int tm = 0; tm < 4; ++tm)
      af[tm] = *(const short8*)&As[(wm*64 + tm*16 + lc)*48 + quad*8];   // A[m=lane&15][k=quad*8+j]
    for (int tn = 0; tn < 4; ++tn)
      bfv[tn] = *(const short8*)&Bs[(wn*64 + tn*16 + lc)*48 + quad*8];  // B[k=quad*8+j][n=lane&15]
    for (int tm = 0; tm < 4; ++tm)
      for (int tn = 0; tn < 4; ++tn)
        acc[tm][tn] = __builtin_amdgcn_mfma_f32_16x16x32_bf16(af[tm], bfv[tn], acc[tm][tn], 0, 0, 0);
    __syncthreads();
  }
  for (int tn = 0; tn < 4; ++tn) {
    const int col = n0 + wn*64 + tn*16 + lc;
    const float bb = bias[col];
    for (int tm = 0; tm < 4; ++tm) {
      const int row = m0 + wm*64 + tm*16 + quad*4;
      for (int r = 0; r < 4; ++r)
        Y[(size_t)(row + r)*256 + col] = f2bf(acc[tm][tn][r] + bb);  // C/D: col=lane&15, row=quad*4+reg
    }
  }
}

// ---------------- per-channel sum / sumsq over Y[65536][256] (bf16) ----------------
__global__ __launch_bounds__(256) void colstats_kernel(
    const u16* __restrict__ Y, float* __restrict__ sums, float* __restrict__ sumsq) {
  const int t = threadIdx.x;
  size_t base = (size_t)blockIdx.x * 256 * 256;
  float s = 0.0f, q = 0.0f;
  for (int r = 0; r < 256; ++r) {
    float v = bf2f(Y[base + (size_t)r*256 + t]);
    s += v; q += v*v;
  }
  atomicAdd(&sums[t], s);
  atomicAdd(&sumsq[t], q);
}

__global__ void bnprep_kernel(const float* __restrict__ sums, const float* __restrict__ sumsq,
                              const float* __restrict__ g, const float* __restrict__ be,
                              float* __restrict__ scale, float* __restrict__ shift) {
  const int t = threadIdx.x;
  const float inv_n = 1.0f / 65536.0f;
  float mean = sums[t] * inv_n;
  float var = sumsq[t] * inv_n - mean*mean;  // biased var, matches jnp.var
  float a = g[t] * rsqrtf(var + 1e-5f);
  scale[t] = a;
  shift[t] = be[t] - mean * a;
}

// ---------------- BN+ReLU, pos-major bf16 output (GEMM2 input) ----------------
__global__ __launch_bounds__(256) void bnrelu_kernel(
    const u16* __restrict__ Y, const float* __restrict__ scale,
    const float* __restrict__ shift, u16* __restrict__ X) {
  const int t = threadIdx.x;
  const float a = scale[t], s = shift[t];
  size_t base = (size_t)blockIdx.x * 16 * 256;
  for (int r = 0; r < 16; ++r) {
    float v = bf2f(Y[base + r*256 + t]) * a + s;
    X[base + r*256 + t] = f2bf(v > 0.0f ? v : 0.0f);
  }
}

// ---------------- BN+ReLU + transpose to [b][c][n] fp32 output ----------------
// grid (64, 1, 16), block 256 (thread = channel).
__global__ __launch_bounds__(256) void bnrelu_tr_kernel(
    const u16* __restrict__ Y, const float* __restrict__ scale,
    const float* __restrict__ shift, float* __restrict__ out) {
  __shared__ u16 tile[256][66];
  const int t = threadIdx.x;
  const int b = blockIdx.z;
  const int n0 = blockIdx.x * 64;
  const float a = scale[t], s = shift[t];
  for (int nn = 0; nn < 64; ++nn) {
    size_t pos = (size_t)b*4096 + n0 + nn;
    float v = bf2f(Y[pos*256 + t]) * a + s;
    tile[t][nn] = f2bf(v > 0.0f ? v : 0.0f);
  }
  __syncthreads();
  const int ln = t & 63, grp = t >> 6;
  for (int p = 0; p < 64; ++p) {
    int oo = p*4 + grp;
    out[((size_t)b*256 + oo)*4096 + n0 + ln] = bf2f(tile[oo][ln]);
  }
}

extern "C" void kernel_launch(void* const* d_in, const int* in_sizes, int n_in,
                              void* d_out, int out_size, void* d_ws, size_t ws_size,
                              hipStream_t stream) {
  const float* xyz1    = (const float*)d_in[0];
  const float* xyz2    = (const float*)d_in[1];
  const float* points1 = (const float*)d_in[2];
  const float* points2 = (const float*)d_in[3];
  const float* w0      = (const float*)d_in[4];
  const float* b0      = (const float*)d_in[5];
  const float* g0      = (const float*)d_in[6];
  const float* be0     = (const float*)d_in[7];
  const float* w1      = (const float*)d_in[8];
  const float* b1      = (const float*)d_in[9];
  const float* g1      = (const float*)d_in[10];
  const float* be1     = (const float*)d_in[11];
  float* out = (float*)d_out;

  // ---- workspace layout (~107 MiB used) ----
  char* ws = (char*)d_ws;
  u16*   A1   = (u16*)ws;                          // [65536][512] bf16, 64 MiB (dead after gemm1)
  u16*   X0   = (u16*)ws;                          // [65536][256] bf16, 32 MiB (overlays dead A1)
  u16*   Y    = (u16*)(ws + (64ull  << 20));       // [65536][256] bf16, 32 MiB
  u16*   p2t  = (u16*)(ws + (96ull  << 20));       // [16*1024][256] bf16, 8 MiB
  int*   idxb = (int*)(ws + (104ull << 20));       // 768 KiB
  float* wgtb = (float*)(ws + (105ull << 20));     // 768 KiB
  u16*   w0b  = (u16*)(ws + (106ull << 20));       // [256][512] bf16, 256 KiB
  u16*   w1b  = (u16*)(ws + (106ull << 20) + (256u << 10)); // [256][256] bf16, 128 KiB
  float* stats= (float*)(ws + (106ull << 20) + (512u << 10)); // 2048 floats

  float* sums0 = stats, *sumsq0 = stats + 256, *scale0 = stats + 512, *shift0 = stats + 768;
  float* sums1 = stats + 1024, *sumsq1 = stats + 1280, *scale1 = stats + 1536, *shift1 = stats + 1792;

  hipMemsetAsync(stats, 0, 2048 * sizeof(float), stream);
  nn3_kernel<<<dim3(64, 16), 256, 0, stream>>>(xyz1, xyz2, idxb, wgtb);
  transpose_cl<<<dim3(16, 4, 16), 256, 0, stream>>>(points2, p2t, 1024, 256);
  transpose_cl<<<dim3(64, 4, 16), 256, 0, stream>>>(points1, A1, 4096, 512);
  cvt_kernel<<<512, 256, 0, stream>>>(w0, w0b, 131072);
  cvt_kernel<<<256, 256, 0, stream>>>(w1, w1b, 65536);
  interp_kernel<<<4096, 256, 0, stream>>>(p2t, idxb, wgtb, A1);
  gemm_kernel<<<dim3(512, 2), 256, 0, stream>>>(A1, w0b, b0, Y, 512);
  colstats_kernel<<<256, 256, 0, stream>>>(Y, sums0, sumsq0);
  bnprep_kernel<<<1, 256, 0, stream>>>(sums0, sumsq0, g0, be0, scale0, shift0);
  bnrelu_kernel<<<4096, 256, 0, stream>>>(Y, scale0, shift0, X0);
  gemm_kernel<<<dim3(512, 2), 256, 0, stream>>>(X0, w1b, b1, Y, 256);
  colstats_kernel<<<256, 256, 0, stream>>>(Y, sums1, sumsq1);
  bnprep_kernel<<<1, 256, 0, stream>>>(sums1, sumsq1, g1, be1, scale1, shift1);
  bnrelu_tr_kernel<<<dim3(64, 1, 16), 256, 0, stream>>>(Y, scale1, shift1, out);
}